// Round 1
// baseline (160.833 us; speedup 1.0000x reference)
//
#include <hip/hip_runtime.h>
#include <math.h>

#define BB 2
#define NN 2048
#define FF 128
#define HH 4
#define HALF 1024

__device__ __forceinline__ float lrelu(float x){ return x > 0.f ? x : 0.2f * x; }

// K0: transpose wv[b][j'][i] -> wvT[b][i][j']
__global__ void k_transpose(const float* __restrict__ wv, float* __restrict__ wvT){
    __shared__ float tile[32][33];
    int b = blockIdx.z;
    int i0 = blockIdx.x * 32;   // column (i) tile of wv
    int j0 = blockIdx.y * 32;   // row (j') tile of wv
    int tx = threadIdx.x & 31, ty = threadIdx.x >> 5;
    const float* src = wv + (size_t)b * HALF * HALF;
    float* dst = wvT + (size_t)b * HALF * HALF;
    #pragma unroll
    for(int l = 0; l < 4; l++){
        int row = ty + l * 8;
        tile[row][tx] = src[(size_t)(j0 + row) * HALF + (i0 + tx)];
    }
    __syncthreads();
    #pragma unroll
    for(int l = 0; l < 4; l++){
        int row = ty + l * 8;
        dst[(size_t)(i0 + row) * HALF + (j0 + tx)] = tile[tx][row];
    }
}

// K1: Wh[b][h][n][f] = sum_k x[b][n][k] * W[h][k][f]
__global__ void k_wh(const float* __restrict__ x, const float* __restrict__ W,
                     float* __restrict__ Wh){
    __shared__ float xs[32][FF];
    int n0 = blockIdx.x * 32;
    int h  = blockIdx.y;
    int b  = blockIdx.z;
    int t  = threadIdx.x;
    const float* xb = x + ((size_t)b * NN + n0) * FF;
    #pragma unroll
    for(int l = 0; l < 16; l++){
        int idx = l * 256 + t;
        xs[idx >> 7][idx & 127] = xb[idx];
    }
    __syncthreads();
    int f = t & 127, rh = t >> 7;
    float acc[16];
    #pragma unroll
    for(int r = 0; r < 16; r++) acc[r] = 0.f;
    const float* Wp = W + (size_t)h * FF * FF + f;
    for(int k = 0; k < FF; k++){
        float w = Wp[(size_t)k * FF];
        #pragma unroll
        for(int r = 0; r < 16; r++) acc[r] += xs[rh * 16 + r][k] * w;
    }
    float* o = Wh + (((size_t)b * HH + h) * NN + n0 + rh * 16) * FF + f;
    #pragma unroll
    for(int r = 0; r < 16; r++) o[(size_t)r * FF] = acc[r];
}

// K2: s[row] = Wh[row]·a_src, d[row] = Wh[row]·a_dst ; row = (b*H+h)*N + n
__global__ void k_sd(const float* __restrict__ Wh, const float* __restrict__ a,
                     float* __restrict__ s, float* __restrict__ d){
    int wid = threadIdx.x >> 6, lane = threadIdx.x & 63;
    int row = blockIdx.x * 4 + wid;
    int h = (row / NN) & (HH - 1);
    const float* wr = Wh + (size_t)row * FF;
    float v0 = wr[lane], v1 = wr[lane + 64];
    const float* ah = a + (size_t)h * 2 * FF;
    float ps = v0 * ah[lane]      + v1 * ah[lane + 64];
    float pd = v0 * ah[FF + lane] + v1 * ah[FF + lane + 64];
    #pragma unroll
    for(int m = 32; m >= 1; m >>= 1){
        ps += __shfl_xor(ps, m);
        pd += __shfl_xor(pd, m);
    }
    if(lane == 0){ s[row] = ps; d[row] = pd; }
}

// K3: denom[b][h][jg] += sum_i att_pre ; grid x=(4 jt * 16 ichunk), y=blk, z=b
__global__ void k_denom(const int* __restrict__ adj, const float* __restrict__ wv,
                        const float* __restrict__ wvT, const float* __restrict__ s,
                        const float* __restrict__ d, float* __restrict__ denom){
    int t = threadIdx.x;
    int jt = blockIdx.x & 3, ich = blockIdx.x >> 2;
    int blk = blockIdx.y, b = blockIdx.z;
    int jl = jt * 256 + t;                   // 0..1023
    int jg = (blk == 0) ? HALF + jl : jl;
    const float* sb = s + (size_t)b * HH * NN;
    const float* db = d + (size_t)b * HH * NN;
    float dj[HH];
    #pragma unroll
    for(int h = 0; h < HH; h++) dj[h] = db[h * NN + jg];
    float acc[HH] = {0.f, 0.f, 0.f, 0.f};
    const int* adjb = adj + (size_t)b * NN * NN;
    const float* wsrc = (blk == 0) ? (wvT + (size_t)b * HALF * HALF)
                                   : (wv  + (size_t)b * HALF * HALF);
    for(int ii = 0; ii < 64; ii++){
        int il = ich * 64 + ii;              // local i 0..1023
        int ig = (blk == 0) ? il : HALF + il;
        int av = adjb[(size_t)ig * NN + jg];
        float wvv = wsrc[(size_t)il * HALF + jl];
        float sv[HH];
        #pragma unroll
        for(int h = 0; h < HH; h++) sv[h] = sb[h * NN + ig];   // uniform -> s_load
        float wm = (av > 0) ? wvv : 0.f;
        #pragma unroll
        for(int h = 0; h < HH; h++)
            acc[h] += __expf(lrelu(sv[h] + dj[h])) * wm;
    }
    #pragma unroll
    for(int h = 0; h < HH; h++)
        atomicAdd(&denom[((size_t)b * HH + h) * NN + jg], acc[h]);
}

// K4: denom -> 1/clip(denom)
__global__ void k_inv(float* denom){
    int i = blockIdx.x * 256 + threadIdx.x;
    denom[i] = 1.0f / fmaxf(denom[i], 1e-12f);
}

// K5: out[b][ig][h*128+f] = elu( sum_j att[ig][j] * Wh[b][h][jg][f] )
// grid: x = i-tile (64), y = blk (2), z = b (2); block = 512 (4h x 128f)
__global__ void k_out(const int* __restrict__ adj, const float* __restrict__ wv,
                      const float* __restrict__ wvT, const float* __restrict__ s,
                      const float* __restrict__ d, const float* __restrict__ inv,
                      const float* __restrict__ Wh, float* __restrict__ out){
    __shared__ float att[32 * 68];          // [j 32][h 4][i 16], stride 68 (16B aligned)
    __shared__ float s_l[HH][16];
    int t = threadIdx.x;
    int it = blockIdx.x, blk = blockIdx.y, b = blockIdx.z;
    int i0 = it * 16;
    int rbase = (blk == 0 ? 0 : HALF) + i0;  // global row base
    if(t < 64){
        int h = t >> 4, i = t & 15;
        s_l[h][i] = s[((size_t)b * HH + h) * NN + rbase + i];
    }
    __syncthreads();
    int f = t & 127, h = t >> 7;
    int a_j = t & 31, a_i = t >> 5;          // phase-A mapping: 32j x 16i
    float acc[16];
    #pragma unroll
    for(int r = 0; r < 16; r++) acc[r] = 0.f;
    const float* wsrc = (blk == 0) ? (wvT + ((size_t)b * HALF + i0 + a_i) * HALF)
                                   : (wv  + ((size_t)b * HALF + i0 + a_i) * HALF);
    const int* adjrow = adj + ((size_t)b * NN + rbase + a_i) * NN;
    const float* dB = d + (size_t)b * HH * NN;
    const float* iB = inv + (size_t)b * HH * NN;
    const float* WhRow = Wh + (((size_t)b * HH + h) * NN) * FF + f;
    int joff = (blk == 0) ? HALF : 0;        // column offset in global j space

    for(int jc = 0; jc < 32; jc++){
        int j0 = jc * 32;
        // ---- Phase A: compute att tile into LDS ----
        {
            int jl = j0 + a_j;
            int jg = joff + jl;
            int av = adjrow[jg];
            float wvv = wsrc[jl];
            float wm = (av > 0) ? wvv : 0.f;
            #pragma unroll
            for(int hh = 0; hh < HH; hh++){
                float e = lrelu(s_l[hh][a_i] + dB[hh * NN + jg]);
                att[a_j * 68 + hh * 16 + a_i] = __expf(e) * wm * iB[hh * NN + jg];
            }
        }
        __syncthreads();
        // ---- Phase B: PV accumulate ----
        #pragma unroll 8
        for(int jl2 = 0; jl2 < 32; jl2++){
            int jg = joff + j0 + jl2;
            float whv = WhRow[(size_t)jg * FF];
            const float4* ap = (const float4*)&att[jl2 * 68 + h * 16];
            #pragma unroll
            for(int q = 0; q < 4; q++){
                float4 a4 = ap[q];
                acc[q * 4 + 0] += a4.x * whv;
                acc[q * 4 + 1] += a4.y * whv;
                acc[q * 4 + 2] += a4.z * whv;
                acc[q * 4 + 3] += a4.w * whv;
            }
        }
        __syncthreads();
    }
    // ---- epilogue: elu + store ----
    #pragma unroll
    for(int i = 0; i < 16; i++){
        float v = acc[i];
        v = (v > 0.f) ? v : expm1f(v);
        out[((size_t)b * NN + rbase + i) * (HH * FF) + h * FF + f] = v;
    }
}

extern "C" void kernel_launch(void* const* d_in, const int* in_sizes, int n_in,
                              void* d_out, int out_size, void* d_ws, size_t ws_size,
                              hipStream_t stream){
    const float* x   = (const float*)d_in[0];
    const float* wv  = (const float*)d_in[1];
    const float* W   = (const float*)d_in[2];
    const float* a   = (const float*)d_in[3];
    const int*   adj = (const int*)d_in[4];
    float* out = (float*)d_out;

    char* ws = (char*)d_ws;
    float* Wh    = (float*)ws;                               // 8,388,608 B
    float* wvT   = (float*)(ws + 8388608);                   // 8,388,608 B
    float* s     = (float*)(ws + 16777216);                  // 65,536 B
    float* dv    = (float*)(ws + 16777216 + 65536);          // 65,536 B
    float* denom = (float*)(ws + 16777216 + 131072);         // 65,536 B

    k_transpose<<<dim3(32, 32, BB), 256, 0, stream>>>(wv, wvT);
    k_wh<<<dim3(64, HH, BB), 256, 0, stream>>>(x, W, Wh);
    k_sd<<<dim3(4096), 256, 0, stream>>>(Wh, a, s, dv);
    hipMemsetAsync(denom, 0, 65536, stream);
    k_denom<<<dim3(64, 2, BB), 256, 0, stream>>>(adj, wv, wvT, s, dv, denom);
    k_inv<<<dim3(64), 256, 0, stream>>>(denom);
    k_out<<<dim3(64, 2, BB), 512, 0, stream>>>(adj, wv, wvT, s, dv, denom, Wh, out);
}

// Round 3
// 79.924 us; speedup vs baseline: 2.0123x; 2.0123x over previous
//
#include <hip/hip_runtime.h>
#include <hip/hip_bf16.h>
#include <math.h>

#define BB 2
#define NN 2048
#define FF 128
#define HH 4
#define HALF 1024

typedef __attribute__((ext_vector_type(8))) short short8;
typedef __attribute__((ext_vector_type(4))) float f32x4;

__device__ __forceinline__ short f2bf(float f){
    __hip_bfloat16 h = __float2bfloat16(f);
    return *reinterpret_cast<short*>(&h);
}
__device__ __forceinline__ float bf2f(short v){
    __hip_bfloat16 h = *reinterpret_cast<__hip_bfloat16*>(&v);
    return __bfloat162float(h);
}

// K0: transpose wv[b][j'][i] -> wvT[b][i][j'] (bf16 out)
__global__ void k_transpose(const float* __restrict__ wv, __hip_bfloat16* __restrict__ wvT){
    __shared__ float tile[32][33];
    int b = blockIdx.z;
    int i0 = blockIdx.x * 32, j0 = blockIdx.y * 32;
    int tx = threadIdx.x & 31, ty = threadIdx.x >> 5;
    const float* src = wv + (size_t)b * HALF * HALF;
    __hip_bfloat16* dst = wvT + (size_t)b * HALF * HALF;
    #pragma unroll
    for(int l = 0; l < 4; l++)
        tile[ty + l * 8][tx] = src[(size_t)(j0 + ty + l * 8) * HALF + (i0 + tx)];
    __syncthreads();
    #pragma unroll
    for(int l = 0; l < 4; l++)
        dst[(size_t)(i0 + ty + l * 8) * HALF + (j0 + tx)] = __float2bfloat16(tile[tx][ty + l * 8]);
}

// K1: Wh[b][h][n][f] = sum_k x[b][n][k] * W[h][k][f]   (fp32)
__global__ void k_wh(const float* __restrict__ x, const float* __restrict__ W,
                     float* __restrict__ Wh){
    __shared__ float xs[32][FF];
    int n0 = blockIdx.x * 32;
    int h  = blockIdx.y;
    int b  = blockIdx.z;
    int t  = threadIdx.x;
    const float* xb = x + ((size_t)b * NN + n0) * FF;
    #pragma unroll
    for(int l = 0; l < 16; l++){
        int idx = l * 256 + t;
        xs[idx >> 7][idx & 127] = xb[idx];
    }
    __syncthreads();
    int f = t & 127, rh = t >> 7;
    float acc[16];
    #pragma unroll
    for(int r = 0; r < 16; r++) acc[r] = 0.f;
    const float* Wp = W + (size_t)h * FF * FF + f;
    for(int k = 0; k < FF; k++){
        float w = Wp[(size_t)k * FF];
        #pragma unroll
        for(int r = 0; r < 16; r++) acc[r] += xs[rh * 16 + r][k] * w;
    }
    float* o = Wh + (((size_t)b * HH + h) * NN + n0 + rh * 16) * FF + f;
    #pragma unroll
    for(int r = 0; r < 16; r++) o[(size_t)r * FF] = acc[r];
}

// K2: s[row] = Wh[row]·a_src, d[row] = Wh[row]·a_dst ; row = (b*H+h)*N + n
__global__ void k_sd(const float* __restrict__ Wh, const float* __restrict__ a,
                     float* __restrict__ s, float* __restrict__ d){
    int wid = threadIdx.x >> 6, lane = threadIdx.x & 63;
    int row = blockIdx.x * 4 + wid;
    int h = (row / NN) & (HH - 1);
    const float* wr = Wh + (size_t)row * FF;
    float v0 = wr[lane], v1 = wr[lane + 64];
    const float* ah = a + (size_t)h * 2 * FF;
    float ps = v0 * ah[lane]      + v1 * ah[lane + 64];
    float pd = v0 * ah[FF + lane] + v1 * ah[FF + lane + 64];
    #pragma unroll
    for(int m = 32; m >= 1; m >>= 1){
        ps += __shfl_xor(ps, m);
        pd += __shfl_xor(pd, m);
    }
    if(lane == 0){ s[row] = ps; d[row] = pd; }
}

// K3: P (bf16, MFMA-A-fragment layout) + column-sum denom via atomics.
// P frag (16i x 32j): lane l -> i = mtg*16 + (l&15), k-chunk = l>>4, e=0..7.
// P offset = ((slice*64 + mtg)*32 + ktg)*512 + lane*8, slice = bb*4+h.
// grid: x = jt(8, 128 j each), y = it(16, 64 i each), z = bb(4). block 256.
__global__ __launch_bounds__(256) void k_att(const int* __restrict__ adj,
        const float* __restrict__ wv, const __hip_bfloat16* __restrict__ wvT,
        const float* __restrict__ s, const float* __restrict__ d,
        short* __restrict__ P, float* __restrict__ denom){
    int t = threadIdx.x;
    int w = t >> 6, lane = t & 63, q = lane >> 4, r = lane & 15;
    int jt = blockIdx.x, it = blockIdx.y, bb = blockIdx.z;
    int b = bb >> 1, blk = bb & 1;
    int jl = jt * 128 + w * 32 + q * 8;        // local col base (8 cols per lane)
    int jg = blk ? jl : HALF + jl;             // global col
    int sl = b * HH;
    float dv[HH][8];
    #pragma unroll
    for(int h = 0; h < HH; h++){
        const float* dp = d + (size_t)(sl + h) * NN + jg;
        float4 d0 = *(const float4*)dp;
        float4 d1 = *(const float4*)(dp + 4);
        dv[h][0]=d0.x; dv[h][1]=d0.y; dv[h][2]=d0.z; dv[h][3]=d0.w;
        dv[h][4]=d1.x; dv[h][5]=d1.y; dv[h][6]=d1.z; dv[h][7]=d1.w;
    }
    float accd[HH][8] = {};
    int ktg = jt * 4 + w;
    #pragma unroll
    for(int mtl = 0; mtl < 4; mtl++){
        int iloc = it * 64 + mtl * 16 + r;
        int ig = blk ? HALF + iloc : iloc;
        const int* ap = adj + ((size_t)b * NN + ig) * NN + jg;
        int4 A0 = *(const int4*)ap;
        int4 A1 = *(const int4*)(ap + 4);
        int aa[8] = {A0.x, A0.y, A0.z, A0.w, A1.x, A1.y, A1.z, A1.w};
        float w8[8];
        if(blk){
            const float* wp = wv + ((size_t)b * HALF + iloc) * HALF + jl;
            float4 W0 = *(const float4*)wp;
            float4 W1 = *(const float4*)(wp + 4);
            w8[0]=W0.x; w8[1]=W0.y; w8[2]=W0.z; w8[3]=W0.w;
            w8[4]=W1.x; w8[5]=W1.y; w8[6]=W1.z; w8[7]=W1.w;
        } else {
            short8 wb = *(const short8*)((const short*)wvT + ((size_t)b * HALF + iloc) * HALF + jl);
            #pragma unroll
            for(int e = 0; e < 8; e++) w8[e] = bf2f(wb[e]);
        }
        float wm[8];
        #pragma unroll
        for(int e = 0; e < 8; e++) wm[e] = aa[e] > 0 ? w8[e] : 0.f;
        int mtg = it * 4 + mtl;
        #pragma unroll
        for(int h = 0; h < HH; h++){
            float sv = s[(size_t)(sl + h) * NN + ig];
            short8 pk;
            #pragma unroll
            for(int e = 0; e < 8; e++){
                float tt = sv + dv[h][e];
                tt = tt > 0.f ? tt : 0.2f * tt;
                float pe = __expf(tt) * wm[e];
                accd[h][e] += pe;
                pk[e] = f2bf(pe);
            }
            *(short8*)(P + (((size_t)(bb * HH + h) * 64 + mtg) * 32 + ktg) * 512 + lane * 8) = pk;
        }
    }
    #pragma unroll
    for(int h = 0; h < HH; h++){
        #pragma unroll
        for(int e = 0; e < 8; e++){
            float v = accd[h][e];
            v += __shfl_xor(v, 1);
            v += __shfl_xor(v, 2);
            v += __shfl_xor(v, 4);
            v += __shfl_xor(v, 8);
            accd[h][e] = v;
        }
    }
    if(r == 0){
        #pragma unroll
        for(int h = 0; h < HH; h++)
            #pragma unroll
            for(int e = 0; e < 8; e++)
                atomicAdd(&denom[(size_t)(sl + h) * NN + jg + e], accd[h][e]);
    }
}

// K4: WhB (bf16, MFMA-B-fragment layout) = Wh[j][f] * 1/clip(denom[j])
// B frag (32k x 16n): lane l -> n = nt*16 + (l&15), k-chunk = l>>4, e=0..7.
// WhB offset = (((b*4+h)*8 + nt)*64 + ktglobal)*512 + lane*8
// grid: x = kt(64), y = h(4), z = b(2). block 256.
__global__ __launch_bounds__(256) void k_scale(const float* __restrict__ Wh,
        const float* __restrict__ denom, short* __restrict__ WhB){
    int t = threadIdx.x, w = t >> 6, lane = t & 63, q = lane >> 4, r = lane & 15;
    int kt = blockIdx.x, h = blockIdx.y, b = blockIdx.z;
    int sl = b * HH + h;
    int jb = kt * 32 + q * 8;
    const float* dp = denom + (size_t)sl * NN + jb;
    float4 D0 = *(const float4*)dp;
    float4 D1 = *(const float4*)(dp + 4);
    float dn[8] = {D0.x,D0.y,D0.z,D0.w,D1.x,D1.y,D1.z,D1.w};
    float inv[8];
    #pragma unroll
    for(int e = 0; e < 8; e++) inv[e] = 1.f / fmaxf(dn[e], 1e-12f);
    #pragma unroll
    for(int ntl = 0; ntl < 2; ntl++){
        int nt = w + ntl * 4;
        int f = nt * 16 + r;
        short8 pk;
        #pragma unroll
        for(int e = 0; e < 8; e++){
            float v = Wh[((size_t)sl * NN + jb + e) * FF + f] * inv[e];
            pk[e] = f2bf(v);
        }
        *(short8*)(WhB + (((size_t)sl * 8 + nt) * 64 + kt) * 512 + lane * 8) = pk;
    }
}

// K5: out = ELU(P @ WhB), MFMA, double-buffered LDS (reg-staged).
// grid: x = Mtile(16, 64 rows), y = h(4), z = bb(4). block 256 (4 waves 2m x 2n).
__global__ __launch_bounds__(256) void k_pv(const short* __restrict__ P,
        const short* __restrict__ WhB, float* __restrict__ out){
    __shared__ short lds[2][6144];    // per buf: A frags 0..3 (1KB each), B frags 4..11
    int t = threadIdx.x;
    int w = t >> 6, lane = t & 63;
    int wm = w >> 1, wn = w & 1;
    int mt = blockIdx.x, h = blockIdx.y, bb = blockIdx.z;
    int b = bb >> 1, blk = bb & 1;
    size_t Pbase = ((size_t)bb * HH + h) * 64 + mt * 4;
    size_t Bb2 = ((size_t)b * HH + h) * 8;
    int koff = blk ? 0 : 32;   // blk=0 rows attend to global cols 1024..2047 (k-tiles 32..63)
    int fr = t >> 6, ln = t & 63;
    f32x4 acc[2][4] = {};
    short8 st0, st1, st2;
#define LOADST(KT) \
    st0 = *(const short8*)(P + ((Pbase + fr) * 32 + (KT)) * 512 + ln * 8); \
    st1 = *(const short8*)(WhB + ((Bb2 + fr) * 64 + koff + (KT)) * 512 + ln * 8); \
    st2 = *(const short8*)(WhB + ((Bb2 + 4 + fr) * 64 + koff + (KT)) * 512 + ln * 8);
#define WRITEST(BUF) \
    *(short8*)&lds[BUF][t * 8] = st0; \
    *(short8*)&lds[BUF][(256 + t) * 8] = st1; \
    *(short8*)&lds[BUF][(512 + t) * 8] = st2;
    LOADST(0)
    WRITEST(0)
    __syncthreads();
    for(int kt = 0; kt < 32; kt++){
        int cur = kt & 1;
        if(kt < 31){ LOADST(kt + 1) }
        short8 af[2], bf[4];
        #pragma unroll
        for(int mi = 0; mi < 2; mi++)
            af[mi] = *(const short8*)&lds[cur][((wm * 2 + mi) * 64 + lane) * 8];
        #pragma unroll
        for(int ni = 0; ni < 4; ni++)
            bf[ni] = *(const short8*)&lds[cur][((4 + wn * 4 + ni) * 64 + lane) * 8];
        #pragma unroll
        for(int mi = 0; mi < 2; mi++)
            #pragma unroll
            for(int ni = 0; ni < 4; ni++)
                acc[mi][ni] = __builtin_amdgcn_mfma_f32_16x16x32_bf16(af[mi], bf[ni], acc[mi][ni], 0, 0, 0);
        __syncthreads();
        if(kt < 31){
            WRITEST(cur ^ 1)
            __syncthreads();
        }
    }
    int rq = lane >> 4, rc = lane & 15;
    #pragma unroll
    for(int mi = 0; mi < 2; mi++){
        #pragma unroll
        for(int ni = 0; ni < 4; ni++){
            int f = (wn * 4 + ni) * 16 + rc;
            #pragma unroll
            for(int rg = 0; rg < 4; rg++){
                int rowl = mt * 64 + wm * 32 + mi * 16 + rq * 4 + rg;
                int rowg = (blk ? HALF : 0) + rowl;
                float v = acc[mi][ni][rg];
                v = v > 0.f ? v : expm1f(v);
                out[((size_t)b * NN + rowg) * (HH * FF) + h * FF + f] = v;
            }
        }
    }
#undef LOADST
#undef WRITEST
}

extern "C" void kernel_launch(void* const* d_in, const int* in_sizes, int n_in,
                              void* d_out, int out_size, void* d_ws, size_t ws_size,
                              hipStream_t stream){
    const float* x   = (const float*)d_in[0];
    const float* wv  = (const float*)d_in[1];
    const float* W   = (const float*)d_in[2];
    const float* a   = (const float*)d_in[3];
    const int*   adj = (const int*)d_in[4];
    float* out = (float*)d_out;

    char* ws = (char*)d_ws;
    short*          P     = (short*)ws;                          // 33,554,432 B
    float*          Wh    = (float*)(ws + 33554432);             //  8,388,608 B
    short*          WhB   = (short*)(ws + 41943040);             //  4,194,304 B
    __hip_bfloat16* wvT   = (__hip_bfloat16*)(ws + 46137344);    //  4,194,304 B
    float*          s     = (float*)(ws + 50331648);             //     65,536 B
    float*          dv    = (float*)(ws + 50397184);             //     65,536 B
    float*          denom = (float*)(ws + 50462720);             //     65,536 B

    k_transpose<<<dim3(32, 32, BB), 256, 0, stream>>>(wv, wvT);
    k_wh<<<dim3(64, HH, BB), 256, 0, stream>>>(x, W, Wh);
    k_sd<<<dim3(4096), 256, 0, stream>>>(Wh, a, s, dv);
    hipMemsetAsync(denom, 0, 65536, stream);
    k_att<<<dim3(8, 16, 4), 256, 0, stream>>>(adj, wv, wvT, s, dv, P, denom);
    k_scale<<<dim3(64, HH, BB), 256, 0, stream>>>(Wh, denom, WhB);
    k_pv<<<dim3(16, HH, 4), 256, 0, stream>>>(P, WhB, out);
}